// Round 26
// baseline (81.876 us; speedup 1.0000x reference)
//
#include <hip/hip_runtime.h>
#include <hip/hip_bf16.h>
#include <stdint.h>

// Problem constants
#define NB    32    // batch
#define CIN   128
#define HH    56
#define WW    56
#define COUT  256

// ws layout: wpack only (bf16, 36*8192 = 294,912 elems)
typedef __attribute__((ext_vector_type(4))) float f32x4;
typedef __attribute__((ext_vector_type(8))) short bf16x8;

__device__ __forceinline__ unsigned short f2bf(float f) {
    union { float f; unsigned u; } v; v.f = f;
    unsigned r = v.u + 0x7FFFu + ((v.u >> 16) & 1u);
    return (unsigned short)(r >> 16);
}

// ---------------------------------------------------------------------------
// build_weight: compose per-output-channel filters.
// wpack layout (R13-verified): [tile(36)][wid4(4)][mf4(4)][lane(64)][kin(8)]
//   elem = tile*8192 + wid4*2048 + mf4*512 + lane*8 + kin; tile = pos*4+cib,
//   o = wid4*64+mf4*16+fl, lane = kpos*16+fl, ci = cib*32+kpos*8+kin.
// (R26 reads it with 8-wave addressing: wid8 -> (wid8>>1, (wid8&1)*2+mf2).)
// ---------------------------------------------------------------------------
__global__ __launch_bounds__(256) void build_weight(
    const float* __restrict__ dict, const float* __restrict__ coef,
    const int* __restrict__ idxw, unsigned short* __restrict__ wpack) {
    int o = blockIdx.x;
    int tid = threadIdx.x;
    bool mode64 = (idxw[1] == 0) && (idxw[3] == 0) && (idxw[5] == 0) &&
                  (idxw[7] == 0) && (idxw[9] == 0) && (idxw[11] == 0) &&
                  (idxw[13] == 0) && (idxw[15] == 0);
    float c[8]; int di[8];
#pragma unroll
    for (int s = 0; s < 8; ++s) {
        c[s]  = coef[o * 8 + s];
        di[s] = mode64 ? idxw[(o * 8 + s) * 2] : idxw[o * 8 + s];
    }
    const int wid = o >> 6, mf = (o >> 4) & 3, fl = o & 15;
    for (int j = tid; j < 9 * 128; j += 256) {
        int pos = j >> 7;          // 0..8
        int ci  = j & 127;
        int kh = pos / 3, kw = pos - kh * 3;
        float v = 0.f;
#pragma unroll
        for (int s = 0; s < 8; ++s)
            v += c[s] * dict[((di[s] * CIN + ci) * 3 + kh) * 3 + kw];
        int tile = pos * 4 + (ci >> 5);
        int kpos = (ci >> 3) & 3, kin = ci & 7;
        wpack[tile * 8192 + wid * 2048 + mf * 512 + (kpos * 16 + fl) * 8 + kin]
            = f2bf(v);
    }
}

// ---------------------------------------------------------------------------
// Main: FUSED pack + implicit-GEMM conv (R26 = R19 tile, 8 THIN waves).
// R25 confirmed R19's 78.2-78.7us floor at 3 waves/SIMD. The untested
// quadrant: more TLP with half-length chains at PRESERVED residency.
//  - Block = 512 threads = 8 waves, 256 Cout x ONE row (same block tile).
//    Wave = 32 Cout x 64 cols: acc[2][4] = 32 AGPR, ~116 unified total ->
//    fits the (512,4) 128-reg cap WITH margin (R18's failure was the
//    64-AGPR body at 148 regs; this is the fix). 2 blocks/CU = 16 waves
//    = 4 waves/SIMD (vs 3), per-tap chain halved (8 MFMA, 2 A-loads).
//  - A: R13 wpack layout, 8-wave addressing ap0 = (wid>>1)*2048 +
//    (wid&1)*1024 + lane*8; af(mf2) = ap0 + mf2*512. Contiguous 1KB
//    wave-loads, ping-pong sets, static index (R15).
//  - Pack: wave wid packs ch {wid*2, wid*2+1} (16 ci), lane = iw, v[16]
//    batched loads -> 2 conflict-free 16B writes x 3 rows (R19 pattern).
//  - Slab [row(3)][ch(16)][iw(64)][kin(8)] stride 512, ONE barrier.
//  - XCD-bijective swizzle kept (R24: losing it doubles FETCH).
// ---------------------------------------------------------------------------
__global__ __launch_bounds__(512, 4) void conv_mfma(
    const float* __restrict__ x,
    const unsigned short* __restrict__ wpack,
    float* __restrict__ out) {
    // slab: elem = (row*16 + ch)*512 + iw*8 + kin ; +128 pad (junk-col reads)
    __shared__ unsigned short Bl[3 * 16 * 512 + 128];

    int tid  = threadIdx.x;
    int lane = tid & 63;
    int wid  = tid >> 6;       // 0..7 = Cout slice of 32 (and pack ch-pair)

    // XCD-bijective swizzle: 1792 = 8 * 224; each XCD gets 4 consecutive b's
    int flat = blockIdx.x;
    int swz  = (flat & 7) * 224 + (flat >> 3);
    int b    = swz / 56;       // 0..31
    int oh   = swz % 56;       // output row

    const int klane = lane >> 4;   // k-group (0..3)
    const int fl    = lane & 15;

    // A-fragment base: af(tile,mf2) = ap0 + tile*8192 + mf2*512 elems
    const unsigned short* ap0 =
        wpack + (size_t)(wid >> 1) * 2048 + (wid & 1) * 1024 + lane * 8;

    // ---- issue A(tile 0) early: latency hides under the pack phase ----
    bf16x8 af[2][2];
#pragma unroll
    for (int mf = 0; mf < 2; ++mf)
        af[0][mf] = *(const bf16x8*)(ap0 + mf * 512);

    // ---- fused pack: lane = iw, wave = ch-pair; batched 16-float loads ----
    {
        const int iw = lane;
        const bool vw = (iw >= 1) && (iw <= WW);
        const int w = vw ? iw - 1 : 0;
#pragma unroll
        for (int row = 0; row < 3; ++row) {
            int h = oh + row - 1;
            bool valid = vw && (h >= 0) && (h < HH);
            int hc = h < 0 ? 0 : (h >= HH ? HH - 1 : h);
            const float* px =
                x + (((size_t)b * CIN + wid * 16) * HH + hc) * WW + w;
            float v[16];
#pragma unroll
            for (int j = 0; j < 16; ++j)          // 16 independent loads
                v[j] = px[(size_t)j * (HH * WW)];
#pragma unroll
            for (int c = 0; c < 2; ++c) {         // one wait, 2 vector writes
                bf16x8 pv;
#pragma unroll
                for (int j = 0; j < 8; ++j)
                    pv[j] = valid ? (short)f2bf(v[c * 8 + j]) : (short)0;
                *(bf16x8*)&Bl[(row * 16 + wid * 2 + c) * 512 + iw * 8] = pv;
            }
        }
    }

    f32x4 acc[2][4];
    f32x4 zero = {0.f, 0.f, 0.f, 0.f};
#pragma unroll
    for (int i = 0; i < 2; ++i)
#pragma unroll
        for (int j = 0; j < 4; ++j) acc[i][j] = zero;

    __syncthreads();   // slab resident; ONLY barrier in the kernel

    const unsigned short* apc = ap0;                       // += 8192/cib
    const unsigned short* bl0 = &Bl[klane * 512 + fl * 8];

#pragma unroll 2
    for (int cib = 0; cib < 4; ++cib) {
        const unsigned short* bcur = bl0 + cib * 2048;     // 4 ch per cib

#pragma unroll
        for (int pos = 0; pos < 9; ++pos) {
            const int kh = pos / 3, kw = pos - kh * 3;
            const int cur = (cib + pos) & 1;   // STATIC under unroll-2 cib

            // ---- prefetch A(next step) into the free set (ping-pong) ----
            if (pos < 8) {
#pragma unroll
                for (int mf = 0; mf < 2; ++mf)
                    af[cur ^ 1][mf] =
                        *(const bf16x8*)(apc + (pos + 1) * 32768 + mf * 512);
            } else if (cib < 3) {
#pragma unroll
                for (int mf = 0; mf < 2; ++mf)
                    af[cur ^ 1][mf] = *(const bf16x8*)(apc + 8192 + mf * 512);
            }

            // ---- B fragments from resident slab (imm-offset ds_read) ----
            bf16x8 bfr[4];
#pragma unroll
            for (int nf = 0; nf < 4; ++nf)
                bfr[nf] = *(const bf16x8*)(bcur + kh * 8192 + (nf * 16 + kw) * 8);

            // ---- 8 MFMA on af[cur] (loaded a full step ago) ----
            __builtin_amdgcn_s_setprio(1);
#pragma unroll
            for (int mf = 0; mf < 2; ++mf)
#pragma unroll
                for (int nf = 0; nf < 4; ++nf)
                    acc[mf][nf] = __builtin_amdgcn_mfma_f32_16x16x32_bf16(
                        af[cur][mf], bfr[nf], acc[mf][nf], 0, 0, 0);
            __builtin_amdgcn_s_setprio(0);
        }
        apc += 8192;
    }

    // Epilogue: C/D layout col = lane&15, row = (lane>>4)*4 + reg (m89-verified)
#pragma unroll
    for (int nf = 0; nf < 4; ++nf) {
        int ow = nf * 16 + fl;
        if (ow < WW) {
#pragma unroll
            for (int mf = 0; mf < 2; ++mf) {
                int ob = wid * 32 + mf * 16 + (lane >> 4) * 4;
                float* dst = out + (((size_t)b * COUT + ob) * HH + oh) * WW + ow;
#pragma unroll
                for (int r = 0; r < 4; ++r)
                    dst[(size_t)r * HH * WW] = acc[mf][nf][r];
            }
        }
    }
}

extern "C" void kernel_launch(void* const* d_in, const int* in_sizes, int n_in,
                              void* d_out, int out_size, void* d_ws, size_t ws_size,
                              hipStream_t stream) {
    const float* x    = (const float*)d_in[0];
    const float* dict = (const float*)d_in[1];
    const float* coef = (const float*)d_in[2];
    const int*   idxw = (const int*)d_in[3];
    float* out = (float*)d_out;

    unsigned short* wpack = (unsigned short*)d_ws;

    build_weight<<<dim3(COUT), dim3(256), 0, stream>>>(dict, coef, idxw, wpack);
    conv_mfma<<<dim3(NB * 56), dim3(512), 0, stream>>>(x, wpack, out);
}